// Round 1
// baseline (129.557 us; speedup 1.0000x reference)
//
#include <hip/hip_runtime.h>
#include <hip/hip_bf16.h>

typedef __attribute__((ext_vector_type(8))) short bf16x8;
typedef __attribute__((ext_vector_type(4))) float f32x4;

#define N_ROWS 8192
#define B_HALF 4096
#define D_DIM 256
#define NTILE 64            // 8192 / 128 tiles per side

// ws layout (bytes)
#define WS_ZN       0                    // ushort [8192][256]  = 4 MB
#define WS_PART     4194304              // float  [8192][64]   = 2 MB
#define WS_POS      6291456              // float  [8192]       = 32 KB
#define WS_DIAG     6324224              // float  [8192]       = 32 KB
#define WS_BSUM     6356992              // float  [32]

__device__ __forceinline__ unsigned short f2bf(float f) {
    __hip_bfloat16 h = __float2bfloat16(f);
    union { __hip_bfloat16 h; unsigned short u; } c; c.h = h; return c.u;
}

__device__ __forceinline__ void async_copy16(const void* g, void* l) {
    __builtin_amdgcn_global_load_lds(
        (const __attribute__((address_space(1))) unsigned int*)g,
        (__attribute__((address_space(3))) unsigned int*)l,
        16, 0, 0);
}

// ---------------- Phase 1: L2-normalize rows, cast to bf16 -------------------
// z = concat([z_augment, z_orig]); 1 wave per row, 4 rows per 256-thread block.
__global__ __launch_bounds__(256) void normalize_k(
    const float* __restrict__ z_orig, const float* __restrict__ z_aug,
    unsigned short* __restrict__ zn)
{
    const int row  = blockIdx.x * 4 + (threadIdx.x >> 6);
    const int lane = threadIdx.x & 63;
    const float* src = (row < B_HALF) ? (z_aug  + (size_t)row * D_DIM)
                                      : (z_orig + (size_t)(row - B_HALF) * D_DIM);
    float4 v = ((const float4*)src)[lane];
    float ss = v.x*v.x + v.y*v.y + v.z*v.z + v.w*v.w;
    #pragma unroll
    for (int m = 1; m < 64; m <<= 1) ss += __shfl_xor(ss, m);
    float inv = 1.0f / fmaxf(sqrtf(ss), 1e-8f);
    ushort4 o;
    o.x = f2bf(v.x * inv); o.y = f2bf(v.y * inv);
    o.z = f2bf(v.z * inv); o.w = f2bf(v.w * inv);
    ((ushort4*)(zn + (size_t)row * D_DIM))[lane] = o;
}

// ---------------- Phase 2: 128x128 S-tile, fused exp-rowsum ------------------
// m97 structure: BK=32, global_load_lds width 16, 16x16x32 bf16 MFMA,
// 2x2 waves each computing 64x64 (4x4 frags of 16x16).
__global__ __launch_bounds__(256) void tile_k(
    const unsigned short* __restrict__ zn,
    float* __restrict__ partials,       // [8192][64]
    float* __restrict__ posv,           // [8192]
    float* __restrict__ diagv)          // [8192]
{
    __shared__ unsigned short As[128 * 32];
    __shared__ unsigned short Bs[128 * 32];
    __shared__ float rowsum[128];

    const int t    = threadIdx.x;
    const int cb   = blockIdx.x;
    const int rb   = blockIdx.y;
    const int rowBase = rb * 128;
    const int colBase = cb * 128;
    const int lane   = t & 63;
    const int wy     = (t >> 7) & 1;     // wave index 0..3 -> (wy,wx) 2x2
    const int wx     = (t >> 6) & 1;
    const int lane15 = lane & 15;
    const int quad   = lane >> 4;

    if (t < 128) rowsum[t] = 0.0f;

    f32x4 acc[4][4];
    #pragma unroll
    for (int i = 0; i < 4; ++i)
        #pragma unroll
        for (int j = 0; j < 4; ++j)
            acc[i][j] = (f32x4){0.f, 0.f, 0.f, 0.f};

    const char* zA = (const char*)zn + (size_t)rowBase * (D_DIM * 2);
    const char* zB = (const char*)zn + (size_t)colBase * (D_DIM * 2);
    const int r0 = t >> 2;               // 0..63: row within 64-row group
    const int c0 = (t & 3) * 16;         // byte offset within 64-byte k-slice
    const int ldsWaveBase = (t & 192) * 16;   // wave * 1024 bytes

    #pragma unroll 1
    for (int kk = 0; kk < 8; ++kk) {
        const int koff = kk * 64;        // byte offset into each 512-byte row
        async_copy16(zA + (size_t)r0 * 512        + koff + c0, (char*)As + ldsWaveBase);
        async_copy16(zA + (size_t)(64 + r0) * 512 + koff + c0, (char*)As + 4096 + ldsWaveBase);
        async_copy16(zB + (size_t)r0 * 512        + koff + c0, (char*)Bs + ldsWaveBase);
        async_copy16(zB + (size_t)(64 + r0) * 512 + koff + c0, (char*)Bs + 4096 + ldsWaveBase);
        __syncthreads();

        bf16x8 a[4], b[4];
        #pragma unroll
        for (int mi = 0; mi < 4; ++mi)
            a[mi] = *(const bf16x8*)((const char*)As +
                     (wy * 64 + mi * 16 + lane15) * 64 + quad * 16);
        #pragma unroll
        for (int ni = 0; ni < 4; ++ni)
            b[ni] = *(const bf16x8*)((const char*)Bs +
                     (wx * 64 + ni * 16 + lane15) * 64 + quad * 16);

        #pragma unroll
        for (int mi = 0; mi < 4; ++mi)
            #pragma unroll
            for (int ni = 0; ni < 4; ++ni)
                acc[mi][ni] = __builtin_amdgcn_mfma_f32_16x16x32_bf16(
                                  a[mi], b[ni], acc[mi][ni], 0, 0, 0);
        __syncthreads();
    }

    // Epilogue: sum_j exp(2*S[i][j]) over this tile's 128 columns.
    // C/D layout: col = lane&15, row = quad*4 + reg.
    #pragma unroll
    for (int mi = 0; mi < 4; ++mi) {
        #pragma unroll
        for (int r = 0; r < 4; ++r) {
            float s = __expf(acc[mi][0][r] * 2.0f) + __expf(acc[mi][1][r] * 2.0f)
                    + __expf(acc[mi][2][r] * 2.0f) + __expf(acc[mi][3][r] * 2.0f);
            s += __shfl_xor(s, 1);
            s += __shfl_xor(s, 2);
            s += __shfl_xor(s, 4);
            s += __shfl_xor(s, 8);
            if (lane15 == 0)
                atomicAdd(&rowsum[wy * 64 + mi * 16 + quad * 4 + r], s);
        }
    }

    // main diagonal (cb==rb) / positive-pair diagonal (cb==rb^32):
    // both land on the tile-local diagonal -> only waves with wy==wx hold them.
    if ((cb == rb || cb == (rb ^ 32)) && wy == wx) {
        if ((lane15 >> 2) == quad) {
            const int r = lane15 & 3;
            #pragma unroll
            for (int mi = 0; mi < 4; ++mi) {
                float v = acc[mi][mi][r];
                int grow = rowBase + wy * 64 + mi * 16 + lane15;
                if (cb == rb) diagv[grow] = v;
                else          posv[grow]  = v;
            }
        }
    }

    __syncthreads();
    if (t < 128)
        partials[(size_t)(rowBase + t) * NTILE + cb] = rowsum[t];
}

// ---------------- Phase 3: per-row loss + block partial sums -----------------
__global__ __launch_bounds__(256) void rowloss_k(
    const float* __restrict__ partials, const float* __restrict__ posv,
    const float* __restrict__ diagv, float* __restrict__ blocksums)
{
    const int i = blockIdx.x * 256 + threadIdx.x;   // 0..8191
    const float* p = partials + (size_t)i * NTILE;
    float s = 0.0f;
    #pragma unroll
    for (int k = 0; k < NTILE; ++k) s += p[k];
    s -= __expf(diagv[i] * 2.0f);                   // drop main-diagonal term
    float loss = logf(s) - posv[i] * 2.0f;

    #pragma unroll
    for (int m = 1; m < 64; m <<= 1) loss += __shfl_xor(loss, m);
    __shared__ float red[4];
    if ((threadIdx.x & 63) == 0) red[threadIdx.x >> 6] = loss;
    __syncthreads();
    if (threadIdx.x == 0)
        blocksums[blockIdx.x] = red[0] + red[1] + red[2] + red[3];
}

// ---------------- Phase 4: final scalar ------------------------------------
__global__ void final_k(const float* __restrict__ blocksums, float* __restrict__ out)
{
    float v = (threadIdx.x < 32) ? blocksums[threadIdx.x] : 0.0f;
    #pragma unroll
    for (int m = 1; m < 64; m <<= 1) v += __shfl_xor(v, m);
    if (threadIdx.x == 0) out[0] = v / (float)N_ROWS;
}

extern "C" void kernel_launch(void* const* d_in, const int* in_sizes, int n_in,
                              void* d_out, int out_size, void* d_ws, size_t ws_size,
                              hipStream_t stream) {
    const float* z_orig = (const float*)d_in[0];
    const float* z_aug  = (const float*)d_in[1];
    char* ws = (char*)d_ws;
    unsigned short* zn  = (unsigned short*)(ws + WS_ZN);
    float* partials     = (float*)(ws + WS_PART);
    float* posv         = (float*)(ws + WS_POS);
    float* diagv        = (float*)(ws + WS_DIAG);
    float* blocksums    = (float*)(ws + WS_BSUM);

    normalize_k<<<N_ROWS / 4, 256, 0, stream>>>(z_orig, z_aug, zn);
    tile_k<<<dim3(NTILE, NTILE), 256, 0, stream>>>(zn, partials, posv, diagv);
    rowloss_k<<<N_ROWS / 256, 256, 0, stream>>>(partials, posv, diagv, blocksums);
    final_k<<<1, 64, 0, stream>>>(blocksums, (float*)d_out);
}

// Round 2
// 118.659 us; speedup vs baseline: 1.0918x; 1.0918x over previous
//
#include <hip/hip_runtime.h>
#include <hip/hip_bf16.h>

typedef __attribute__((ext_vector_type(8))) short bf16x8;
typedef __attribute__((ext_vector_type(4))) float f32x4;

#define N_ROWS 8192
#define B_HALF 4096
#define D_DIM 256
#define NTILE 64            // 8192 / 128 tiles per side
#define NUT   2080          // 64*65/2 upper-triangle tiles
#define EXP2C 2.885390081777927f   // 2*log2(e): exp(2S) = exp2(S*EXP2C)

// ws layout (bytes)
#define WS_ZN       0                    // ushort [8192][256]  = 4 MB
#define WS_PART     4194304              // float  [64][8192]   = 2 MB (TRANSPOSED)
#define WS_POS      6291456              // float  [8192]       raw S_pos
#define WS_DIAG     6324224              // float  [8192]       exp2(S_ii*EXP2C)
#define WS_ACC      6356992              // float  accum
#define WS_CNT      6356996              // uint   counter

__device__ __forceinline__ unsigned short f2bf(float f) {
    __hip_bfloat16 h = __float2bfloat16(f);
    union { __hip_bfloat16 h; unsigned short u; } c; c.h = h; return c.u;
}

__device__ __forceinline__ float fexp2(float x) {
#if __has_builtin(__builtin_amdgcn_exp2f)
    return __builtin_amdgcn_exp2f(x);
#else
    return exp2f(x);
#endif
}

__device__ __forceinline__ void async_copy16(const void* g, void* l) {
    __builtin_amdgcn_global_load_lds(
        (const __attribute__((address_space(1))) unsigned int*)g,
        (__attribute__((address_space(3))) unsigned int*)l,
        16, 0, 0);
}

// ---------------- Phase 1: L2-normalize rows, cast to bf16 -------------------
__global__ __launch_bounds__(256) void normalize_k(
    const float* __restrict__ z_orig, const float* __restrict__ z_aug,
    unsigned short* __restrict__ zn, float* __restrict__ accum,
    unsigned int* __restrict__ cnt)
{
    if (blockIdx.x == 0 && threadIdx.x == 0) { *accum = 0.0f; *cnt = 0u; }
    const int row  = blockIdx.x * 4 + (threadIdx.x >> 6);
    const int lane = threadIdx.x & 63;
    const float* src = (row < B_HALF) ? (z_aug  + (size_t)row * D_DIM)
                                      : (z_orig + (size_t)(row - B_HALF) * D_DIM);
    float4 v = ((const float4*)src)[lane];
    float ss = v.x*v.x + v.y*v.y + v.z*v.z + v.w*v.w;
    #pragma unroll
    for (int m = 1; m < 64; m <<= 1) ss += __shfl_xor(ss, m);
    float inv = 1.0f / fmaxf(sqrtf(ss), 1e-8f);
    ushort4 o;
    o.x = f2bf(v.x * inv); o.y = f2bf(v.y * inv);
    o.z = f2bf(v.z * inv); o.w = f2bf(v.w * inv);
    ((ushort4*)(zn + (size_t)row * D_DIM))[lane] = o;
}

// ---------------- Phase 2: upper-triangle 128x128 S-tiles --------------------
// Symmetric: each off-diag tile emits BOTH rowsums (for rb-block rows) and
// colsums (for cb-block rows). partials is [tile_k_index][row] transposed so
// writes and loss-phase reads are coalesced.
__global__ __launch_bounds__(256) void tile_k(
    const unsigned short* __restrict__ zn,
    float* __restrict__ partials,       // [64][8192]
    float* __restrict__ posv,           // [8192] raw S_pos
    float* __restrict__ diagE)          // [8192] exp2(S_ii*EXP2C)
{
    __shared__ unsigned short As[128 * 32];
    __shared__ unsigned short Bs[128 * 32];
    __shared__ float rs[2][128];
    __shared__ float cs[2][128];

    const int bid = blockIdx.x;
    // decode upper-triangular (rb, cb), cb >= rb; C(r) = r*(129-r)/2
    int rb = (int)((129.0f - sqrtf(16641.0f - 8.0f * (float)bid)) * 0.5f);
    rb = rb < 0 ? 0 : (rb > 63 ? 63 : rb);
    while ((rb + 1) * (129 - (rb + 1)) / 2 <= bid) ++rb;
    while (rb * (129 - rb) / 2 > bid) --rb;
    const int cb = rb + (bid - rb * (129 - rb) / 2);

    const int t    = threadIdx.x;
    const int rowBase = rb * 128;
    const int colBase = cb * 128;
    const int lane   = t & 63;
    const int wy     = (t >> 7) & 1;
    const int wx     = (t >> 6) & 1;
    const int lane15 = lane & 15;
    const int quad   = lane >> 4;

    f32x4 acc[4][4];
    #pragma unroll
    for (int i = 0; i < 4; ++i)
        #pragma unroll
        for (int j = 0; j < 4; ++j)
            acc[i][j] = (f32x4){0.f, 0.f, 0.f, 0.f};

    const char* zA = (const char*)zn + (size_t)rowBase * (D_DIM * 2);
    const char* zB = (const char*)zn + (size_t)colBase * (D_DIM * 2);
    const int r0 = t >> 2;
    const int c0 = (t & 3) * 16;
    const int ldsWaveBase = (t & 192) * 16;

    #pragma unroll 1
    for (int kk = 0; kk < 8; ++kk) {
        const int koff = kk * 64;
        async_copy16(zA + (size_t)r0 * 512        + koff + c0, (char*)As + ldsWaveBase);
        async_copy16(zA + (size_t)(64 + r0) * 512 + koff + c0, (char*)As + 4096 + ldsWaveBase);
        async_copy16(zB + (size_t)r0 * 512        + koff + c0, (char*)Bs + ldsWaveBase);
        async_copy16(zB + (size_t)(64 + r0) * 512 + koff + c0, (char*)Bs + 4096 + ldsWaveBase);
        __syncthreads();

        bf16x8 a[4], b[4];
        #pragma unroll
        for (int mi = 0; mi < 4; ++mi)
            a[mi] = *(const bf16x8*)((const char*)As +
                     (wy * 64 + mi * 16 + lane15) * 64 + quad * 16);
        #pragma unroll
        for (int ni = 0; ni < 4; ++ni)
            b[ni] = *(const bf16x8*)((const char*)Bs +
                     (wx * 64 + ni * 16 + lane15) * 64 + quad * 16);

        #pragma unroll
        for (int mi = 0; mi < 4; ++mi)
            #pragma unroll
            for (int ni = 0; ni < 4; ++ni)
                acc[mi][ni] = __builtin_amdgcn_mfma_f32_16x16x32_bf16(
                                  a[mi], b[ni], acc[mi][ni], 0, 0, 0);
        __syncthreads();
    }

    // C/D layout: m-row = quad*4 + reg, n-col = lane15 (validated round 1).
    // --- extract diagonals BEFORE exp-in-place ---
    const bool diagLane = (wy == wx) && ((lane15 >> 2) == quad);
    const int  rsel = lane15 & 3;
    if (cb == rb && diagLane) {
        #pragma unroll
        for (int mi = 0; mi < 4; ++mi) {
            int grow = rowBase + wy * 64 + mi * 16 + lane15;
            diagE[grow] = fexp2(acc[mi][mi][rsel] * EXP2C);
        }
    }
    if (cb == rb + 32 && diagLane) {   // positive-pair diagonal (rb<32 only)
        #pragma unroll
        for (int mi = 0; mi < 4; ++mi) {
            int grow = rowBase + wy * 64 + mi * 16 + lane15;
            float v = acc[mi][mi][rsel];
            posv[grow] = v;
            posv[grow + B_HALF] = v;   // symmetric partner row
        }
    }

    // --- exp(2*S) in place ---
    #pragma unroll
    for (int mi = 0; mi < 4; ++mi)
        #pragma unroll
        for (int ni = 0; ni < 4; ++ni)
            #pragma unroll
            for (int r = 0; r < 4; ++r)
                acc[mi][ni][r] = fexp2(acc[mi][ni][r] * EXP2C);

    // --- row sums (reduce over n = lane15 and ni) ---
    #pragma unroll
    for (int mi = 0; mi < 4; ++mi)
        #pragma unroll
        for (int r = 0; r < 4; ++r) {
            float s = acc[mi][0][r] + acc[mi][1][r] + acc[mi][2][r] + acc[mi][3][r];
            s += __shfl_xor(s, 1);
            s += __shfl_xor(s, 2);
            s += __shfl_xor(s, 4);
            s += __shfl_xor(s, 8);
            if (lane15 == 0) rs[wx][wy * 64 + mi * 16 + quad * 4 + r] = s;
        }

    // --- col sums (reduce over m = quad,reg,mi); off-diagonal tiles only ---
    if (cb != rb) {
        #pragma unroll
        for (int ni = 0; ni < 4; ++ni) {
            float s = 0.0f;
            #pragma unroll
            for (int mi = 0; mi < 4; ++mi)
                s += acc[mi][ni][0] + acc[mi][ni][1] + acc[mi][ni][2] + acc[mi][ni][3];
            s += __shfl_xor(s, 16);
            s += __shfl_xor(s, 32);
            if (quad == 0) cs[wy][wx * 64 + ni * 16 + lane15] = s;
        }
    }

    __syncthreads();
    if (t < 128) {
        partials[(size_t)cb * N_ROWS + rowBase + t] = rs[0][t] + rs[1][t];
    } else if (cb != rb) {
        const int t2 = t - 128;
        partials[(size_t)rb * N_ROWS + colBase + t2] = cs[0][t2] + cs[1][t2];
    }
}

// ---------------- Phase 3: per-row loss + grid reduction (last block) --------
__global__ __launch_bounds__(256) void loss_k(
    const float* __restrict__ partials, const float* __restrict__ posv,
    const float* __restrict__ diagE, float* __restrict__ accum,
    unsigned int* __restrict__ cnt, float* __restrict__ out)
{
    const int i = blockIdx.x * 256 + threadIdx.x;
    float s = 0.0f;
    #pragma unroll
    for (int k = 0; k < NTILE; ++k) s += partials[(size_t)k * N_ROWS + i];
    s -= diagE[i];                              // drop main-diagonal term
    float loss = __logf(s) - 2.0f * posv[i];    // logits = 2*S (tau = 0.5)

    #pragma unroll
    for (int m = 1; m < 64; m <<= 1) loss += __shfl_xor(loss, m);
    __shared__ float red[4];
    if ((threadIdx.x & 63) == 0) red[threadIdx.x >> 6] = loss;
    __syncthreads();
    if (threadIdx.x == 0) {
        float bs = red[0] + red[1] + red[2] + red[3];
        atomicAdd(accum, bs);
        __threadfence();
        unsigned int old = atomicAdd(cnt, 1u);
        if (old == 31u) {                       // last of 32 blocks
            __threadfence();
            float total = atomicAdd(accum, 0.0f);
            out[0] = total * (1.0f / (float)N_ROWS);
        }
    }
}

extern "C" void kernel_launch(void* const* d_in, const int* in_sizes, int n_in,
                              void* d_out, int out_size, void* d_ws, size_t ws_size,
                              hipStream_t stream) {
    const float* z_orig = (const float*)d_in[0];
    const float* z_aug  = (const float*)d_in[1];
    char* ws = (char*)d_ws;
    unsigned short* zn  = (unsigned short*)(ws + WS_ZN);
    float* partials     = (float*)(ws + WS_PART);
    float* posv         = (float*)(ws + WS_POS);
    float* diagE        = (float*)(ws + WS_DIAG);
    float* accum        = (float*)(ws + WS_ACC);
    unsigned int* cnt   = (unsigned int*)(ws + WS_CNT);

    normalize_k<<<N_ROWS / 4, 256, 0, stream>>>(z_orig, z_aug, zn, accum, cnt);
    tile_k<<<NUT, 256, 0, stream>>>(zn, partials, posv, diagE);
    loss_k<<<N_ROWS / 256, 256, 0, stream>>>(partials, posv, diagE, accum, cnt,
                                             (float*)d_out);
}

// Round 3
// 103.746 us; speedup vs baseline: 1.2488x; 1.1437x over previous
//
#include <hip/hip_runtime.h>
#include <hip/hip_bf16.h>

typedef __attribute__((ext_vector_type(8))) short bf16x8;
typedef __attribute__((ext_vector_type(4))) float f32x4;

#define N_ROWS 8192
#define B_HALF 4096
#define D_DIM 256
#define NUT   2080          // 64*65/2 upper-triangle 128x128 tiles
#define EXP2C 2.885390081777927f   // 2*log2(e): exp(2S) = exp2(S*EXP2C)

// ws layout (bytes)
#define WS_ZN       0                    // ushort [8192][256]  = 4 MB
#define WS_ROWACC   4194304              // float  [8192]  sum_j exp(2 S_ij)
#define WS_POS      4227072              // float  [8192]  raw S_pos
#define WS_DIAG     4259840              // float  [8192]  exp2(S_ii*EXP2C)
#define WS_ACC      4292608              // float  final accum
#define WS_CNT      4292612              // uint   block counter

__device__ __forceinline__ unsigned short f2bf(float f) {
    __hip_bfloat16 h = __float2bfloat16(f);
    union { __hip_bfloat16 h; unsigned short u; } c; c.h = h; return c.u;
}

__device__ __forceinline__ float fexp2(float x) { return exp2f(x); }

__device__ __forceinline__ void async_copy16(const void* g, void* l) {
    __builtin_amdgcn_global_load_lds(
        (const __attribute__((address_space(1))) unsigned int*)g,
        (__attribute__((address_space(3))) unsigned int*)l,
        16, 0, 0);
}

// ---------------- Phase 1: L2-normalize rows, cast to bf16; zero accums ------
__global__ __launch_bounds__(256) void normalize_k(
    const float* __restrict__ z_orig, const float* __restrict__ z_aug,
    unsigned short* __restrict__ zn, float* __restrict__ rowAcc,
    float* __restrict__ accum, unsigned int* __restrict__ cnt)
{
    if (blockIdx.x == 0 && threadIdx.x == 0) { *accum = 0.0f; *cnt = 0u; }
    const int row  = blockIdx.x * 4 + (threadIdx.x >> 6);
    const int lane = threadIdx.x & 63;
    if (lane == 0) rowAcc[row] = 0.0f;       // zero before tile_k (stream order)
    const float* src = (row < B_HALF) ? (z_aug  + (size_t)row * D_DIM)
                                      : (z_orig + (size_t)(row - B_HALF) * D_DIM);
    float4 v = ((const float4*)src)[lane];
    float ss = v.x*v.x + v.y*v.y + v.z*v.z + v.w*v.w;
    #pragma unroll
    for (int m = 1; m < 64; m <<= 1) ss += __shfl_xor(ss, m);
    float inv = 1.0f / fmaxf(sqrtf(ss), 1e-8f);
    ushort4 o;
    o.x = f2bf(v.x * inv); o.y = f2bf(v.y * inv);
    o.z = f2bf(v.z * inv); o.w = f2bf(v.w * inv);
    ((ushort4*)(zn + (size_t)row * D_DIM))[lane] = o;
}

// ---------------- Phase 2: upper-triangle 128x128 S-tiles --------------------
// BK=64 (4 K-iters, 8 barriers). XOR-swizzled LDS: physical 16B slot p of row
// r holds logical K-chunk p^(r&7); permutation applied on the GLOBAL address
// side since global_load_lds forces LDS dest = base + lane*16.
__global__ __launch_bounds__(256, 3) void tile_k(
    const unsigned short* __restrict__ zn,
    float* __restrict__ rowAcc,         // [8192] += sum_j exp(2 S_ij) partials
    float* __restrict__ posv,           // [8192] raw S_pos
    float* __restrict__ diagE)          // [8192] exp2(S_ii*EXP2C)
{
    __shared__ unsigned short As[128 * 64];   // 128 rows x 128 B
    __shared__ unsigned short Bs[128 * 64];

    const int bid = blockIdx.x;
    // decode upper-triangular (rb, cb), cb >= rb; C(r) = r*(129-r)/2
    int rb = (int)((129.0f - sqrtf(16641.0f - 8.0f * (float)bid)) * 0.5f);
    rb = rb < 0 ? 0 : (rb > 63 ? 63 : rb);
    while ((rb + 1) * (129 - (rb + 1)) / 2 <= bid) ++rb;
    while (rb * (129 - rb) / 2 > bid) --rb;
    const int cb = rb + (bid - rb * (129 - rb) / 2);

    const int t    = threadIdx.x;
    const int rowBase = rb * 128;
    const int colBase = cb * 128;
    const int lane   = t & 63;
    const int w      = t >> 6;
    const int wy     = w >> 1;
    const int wx     = w & 1;
    const int lane15 = lane & 15;
    const int quad   = lane >> 4;

    f32x4 acc[4][4];
    #pragma unroll
    for (int i = 0; i < 4; ++i)
        #pragma unroll
        for (int j = 0; j < 4; ++j)
            acc[i][j] = (f32x4){0.f, 0.f, 0.f, 0.f};

    const char* zA = (const char*)zn + (size_t)rowBase * 512;
    const char* zB = (const char*)zn + (size_t)colBase * 512;

    // staging: shot s covers rows [s*32, s*32+32); thread t -> row s*32+(t>>3),
    // physical slot p=t&7 -> fetch logical chunk q = p ^ (row&7)
    const int rloc = t >> 3;                 // 0..31
    const int q16  = ((t & 7) ^ (rloc & 7)) * 16;
    // fragment reads: row rA+mi*16; swizzle term is mi-independent
    const int rA = wy * 64 + lane15;
    const int rB = wx * 64 + lane15;
    const int sw = lane15 & 7;

    #pragma unroll 1
    for (int kk = 0; kk < 4; ++kk) {
        const int koff = kk * 128;
        #pragma unroll
        for (int s = 0; s < 4; ++s) {
            const size_t goff = (size_t)(s * 32 + rloc) * 512 + koff + q16;
            async_copy16(zA + goff, (char*)As + s * 4096 + w * 1024);
            async_copy16(zB + goff, (char*)Bs + s * 4096 + w * 1024);
        }
        __syncthreads();

        #pragma unroll
        for (int kk2 = 0; kk2 < 2; ++kk2) {
            const int pa = (((kk2 * 4 + quad) ^ sw) << 4);
            bf16x8 a[4], b[4];
            #pragma unroll
            for (int mi = 0; mi < 4; ++mi)
                a[mi] = *(const bf16x8*)((const char*)As + (rA + mi * 16) * 128 + pa);
            #pragma unroll
            for (int ni = 0; ni < 4; ++ni)
                b[ni] = *(const bf16x8*)((const char*)Bs + (rB + ni * 16) * 128 + pa);
            #pragma unroll
            for (int mi = 0; mi < 4; ++mi)
                #pragma unroll
                for (int ni = 0; ni < 4; ++ni)
                    acc[mi][ni] = __builtin_amdgcn_mfma_f32_16x16x32_bf16(
                                      a[mi], b[ni], acc[mi][ni], 0, 0, 0);
        }
        __syncthreads();
    }

    // C/D layout: m-row = quad*4 + reg, n-col = lane15 (validated rounds 1-2).
    // --- diagonals BEFORE exp-in-place ---
    const bool diagLane = (wy == wx) && ((lane15 >> 2) == quad);
    const int  rsel = lane15 & 3;
    if (cb == rb && diagLane) {
        #pragma unroll
        for (int mi = 0; mi < 4; ++mi) {
            int grow = rowBase + wy * 64 + mi * 16 + lane15;
            diagE[grow] = fexp2(acc[mi][mi][rsel] * EXP2C);
        }
    }
    if (cb == rb + 32 && diagLane) {   // positive-pair diagonal
        #pragma unroll
        for (int mi = 0; mi < 4; ++mi) {
            int grow = rowBase + wy * 64 + mi * 16 + lane15;
            float v = acc[mi][mi][rsel];
            posv[grow] = v;
            posv[grow + B_HALF] = v;
        }
    }

    // --- exp(2*S) in place ---
    #pragma unroll
    for (int mi = 0; mi < 4; ++mi)
        #pragma unroll
        for (int ni = 0; ni < 4; ++ni)
            #pragma unroll
            for (int r = 0; r < 4; ++r)
                acc[mi][ni][r] = fexp2(acc[mi][ni][r] * EXP2C);

    // --- row sums (over n): direct global atomics, no barrier needed ---
    #pragma unroll
    for (int mi = 0; mi < 4; ++mi)
        #pragma unroll
        for (int r = 0; r < 4; ++r) {
            float s = acc[mi][0][r] + acc[mi][1][r] + acc[mi][2][r] + acc[mi][3][r];
            s += __shfl_xor(s, 1);
            s += __shfl_xor(s, 2);
            s += __shfl_xor(s, 4);
            s += __shfl_xor(s, 8);
            if (lane15 == 0)
                atomicAdd(&rowAcc[rowBase + wy * 64 + mi * 16 + quad * 4 + r], s);
        }

    // --- col sums (over m); off-diagonal tiles only ---
    if (cb != rb) {
        #pragma unroll
        for (int ni = 0; ni < 4; ++ni) {
            float s = 0.0f;
            #pragma unroll
            for (int mi = 0; mi < 4; ++mi)
                s += acc[mi][ni][0] + acc[mi][ni][1] + acc[mi][ni][2] + acc[mi][ni][3];
            s += __shfl_xor(s, 16);
            s += __shfl_xor(s, 32);
            if (quad == 0)
                atomicAdd(&rowAcc[colBase + wx * 64 + ni * 16 + lane15], s);
        }
    }
}

// ---------------- Phase 3: per-row loss + grid reduction (last block) --------
__global__ __launch_bounds__(256) void loss_k(
    const float* __restrict__ rowAcc, const float* __restrict__ posv,
    const float* __restrict__ diagE, float* __restrict__ accum,
    unsigned int* __restrict__ cnt, float* __restrict__ out)
{
    const int i = blockIdx.x * 256 + threadIdx.x;
    float s = rowAcc[i] - diagE[i];             // drop main-diagonal term
    float loss = __logf(s) - 2.0f * posv[i];    // logits = 2*S (tau = 0.5)

    #pragma unroll
    for (int m = 1; m < 64; m <<= 1) loss += __shfl_xor(loss, m);
    __shared__ float red[4];
    if ((threadIdx.x & 63) == 0) red[threadIdx.x >> 6] = loss;
    __syncthreads();
    if (threadIdx.x == 0) {
        float bs = red[0] + red[1] + red[2] + red[3];
        atomicAdd(accum, bs);
        __threadfence();
        unsigned int old = atomicAdd(cnt, 1u);
        if (old == 31u) {                       // last of 32 blocks
            __threadfence();
            float total = atomicAdd(accum, 0.0f);
            out[0] = total * (1.0f / (float)N_ROWS);
        }
    }
}

extern "C" void kernel_launch(void* const* d_in, const int* in_sizes, int n_in,
                              void* d_out, int out_size, void* d_ws, size_t ws_size,
                              hipStream_t stream) {
    const float* z_orig = (const float*)d_in[0];
    const float* z_aug  = (const float*)d_in[1];
    char* ws = (char*)d_ws;
    unsigned short* zn  = (unsigned short*)(ws + WS_ZN);
    float* rowAcc       = (float*)(ws + WS_ROWACC);
    float* posv         = (float*)(ws + WS_POS);
    float* diagE        = (float*)(ws + WS_DIAG);
    float* accum        = (float*)(ws + WS_ACC);
    unsigned int* cnt   = (unsigned int*)(ws + WS_CNT);

    normalize_k<<<N_ROWS / 4, 256, 0, stream>>>(z_orig, z_aug, zn, rowAcc, accum, cnt);
    tile_k<<<NUT, 256, 0, stream>>>(zn, rowAcc, posv, diagE);
    loss_k<<<N_ROWS / 256, 256, 0, stream>>>(rowAcc, posv, diagE, accum, cnt,
                                             (float*)d_out);
}